// Round 1
// baseline (221.851 us; speedup 1.0000x reference)
//
#include <hip/hip_runtime.h>

#define BS_   4
#define SEQ_  4096
#define DIM_  768
#define NH_   12
#define HD_   64
#define LK_   256

typedef __attribute__((ext_vector_type(8))) short          bf8;
typedef __attribute__((ext_vector_type(8))) unsigned short us8;
typedef __attribute__((ext_vector_type(4))) float          f32x4;

__device__ __forceinline__ unsigned short f2bf(float f) {
  unsigned u = __builtin_bit_cast(unsigned, f);
  u += 0x7fffu + ((u >> 16) & 1u);   // round-to-nearest-even
  return (unsigned short)(u >> 16);
}

__device__ __forceinline__ us8 cvt8(const float* __restrict__ p) {
  const float4 a = *(const float4*)p;
  const float4 b = *(const float4*)(p + 4);
  us8 r;
  r[0] = f2bf(a.x); r[1] = f2bf(a.y); r[2] = f2bf(a.z); r[3] = f2bf(a.w);
  r[4] = f2bf(b.x); r[5] = f2bf(b.y); r[6] = f2bf(b.z); r[7] = f2bf(b.w);
  return r;
}

// ---------------------------------------------------------------------------
// Pool: pooled[b,l,d] = (1/16) sum_w keep(b,l*16+w) * x[b,l*16+w,d]  (bf16 out)
// frac[b,l] = kept_count / 16
// ---------------------------------------------------------------------------
__global__ __launch_bounds__(256) void pool_kernel(
    const float* __restrict__ key, const float* __restrict__ value,
    const float* __restrict__ mask,
    unsigned short* __restrict__ pk, unsigned short* __restrict__ pv,
    float* __restrict__ frac)
{
  const int blk = blockIdx.x;          // 0..1023
  const int b = blk >> 8;
  const int l = blk & 255;
  const int tid = threadIdx.x;
  __shared__ float keep[16];
  if (tid < 16) keep[tid] = (mask[b * SEQ_ + l * 16 + tid] >= 0.f) ? 1.f : 0.f;
  __syncthreads();
  float ak0 = 0.f, ak1 = 0.f, ak2 = 0.f, av0 = 0.f, av1 = 0.f, av2 = 0.f;
  #pragma unroll 1
  for (int w = 0; w < 16; ++w) {
    if (keep[w] != 0.f) {              // block-uniform branch
      const size_t row = (size_t)(b * SEQ_ + l * 16 + w) * DIM_;
      const float* kr = key + row;
      const float* vr = value + row;
      ak0 += kr[tid]; ak1 += kr[tid + 256]; ak2 += kr[tid + 512];
      av0 += vr[tid]; av1 += vr[tid + 256]; av2 += vr[tid + 512];
    }
  }
  const size_t o = (size_t)(b * LK_ + l) * DIM_;
  const float s = 1.f / 16.f;
  pk[o + tid] = f2bf(ak0 * s); pk[o + tid + 256] = f2bf(ak1 * s); pk[o + tid + 512] = f2bf(ak2 * s);
  pv[o + tid] = f2bf(av0 * s); pv[o + tid + 256] = f2bf(av1 * s); pv[o + tid + 512] = f2bf(av2 * s);
  if (tid == 0) {
    float c = 0.f;
    for (int w = 0; w < 16; ++w) c += keep[w];
    frac[b * LK_ + l] = c * s;
  }
}

// ---------------------------------------------------------------------------
// C = A @ B^T (+ epilogue).  A: [M][768] (f32 or bf16), B: [768][768] f32
// (converted to bf16 in the stager).  128x128 tile, BK=32, 4 waves (2x2 of
// 64x64), mfma_f32_16x16x32_bf16.
// MODE 0: out_bf16 = (acc + bias[c]) * scale          (Q projection)
// MODE 1: out_bf16 = acc + frac[r] * bias[c]          (pooled K/V projection)
// MODE 2: out_f32  = acc + bias[c]                    (output projection)
// ---------------------------------------------------------------------------
template<int AF32, int MODE>
__global__ __launch_bounds__(256) void gemm_bt(
    const void* __restrict__ Aptr, const float* __restrict__ Bw,
    const float* __restrict__ bias, const float* __restrict__ frac,
    void* __restrict__ Cout, int M, float scale)
{
  constexpr int K = DIM_;
  __shared__ unsigned short lA[128 * 32];
  __shared__ unsigned short lB[128 * 32];
  const int tid  = threadIdx.x;
  const int lane = tid & 63;
  const int wave = tid >> 6;
  const int brow = blockIdx.x * 128;
  const int bcol = blockIdx.y * 128;
  const int wr   = (wave >> 1) * 64;
  const int wc   = (wave & 1) * 64;
  const int fr   = lane & 15;
  const int fk   = (lane >> 4) * 8;

  f32x4 acc[4][4];
  #pragma unroll
  for (int i = 0; i < 4; ++i)
    #pragma unroll
    for (int j = 0; j < 4; ++j) acc[i][j] = (f32x4){0.f, 0.f, 0.f, 0.f};

  const int srow = tid >> 2;           // 0..63
  const int schk = (tid & 3) * 8;      // k element offset

  for (int k0 = 0; k0 < K; k0 += 32) {
    us8 a0, a1, b0, b1;
    if (AF32) {
      const float* A = (const float*)Aptr;
      a0 = cvt8(A + (size_t)(brow + srow) * K + k0 + schk);
      a1 = cvt8(A + (size_t)(brow + srow + 64) * K + k0 + schk);
    } else {
      const unsigned short* A = (const unsigned short*)Aptr;
      a0 = *(const us8*)(A + (size_t)(brow + srow) * K + k0 + schk);
      a1 = *(const us8*)(A + (size_t)(brow + srow + 64) * K + k0 + schk);
    }
    b0 = cvt8(Bw + (size_t)(bcol + srow) * K + k0 + schk);
    b1 = cvt8(Bw + (size_t)(bcol + srow + 64) * K + k0 + schk);
    __syncthreads();
    *(us8*)&lA[srow * 32 + schk]        = a0;
    *(us8*)&lA[(srow + 64) * 32 + schk] = a1;
    *(us8*)&lB[srow * 32 + schk]        = b0;
    *(us8*)&lB[(srow + 64) * 32 + schk] = b1;
    __syncthreads();
    bf8 af[4], bfv[4];
    #pragma unroll
    for (int mi = 0; mi < 4; ++mi)
      af[mi] = *(const bf8*)&lA[(wr + mi * 16 + fr) * 32 + fk];
    #pragma unroll
    for (int ni = 0; ni < 4; ++ni)
      bfv[ni] = *(const bf8*)&lB[(wc + ni * 16 + fr) * 32 + fk];
    #pragma unroll
    for (int mi = 0; mi < 4; ++mi)
      #pragma unroll
      for (int ni = 0; ni < 4; ++ni)
        acc[mi][ni] = __builtin_amdgcn_mfma_f32_16x16x32_bf16(af[mi], bfv[ni], acc[mi][ni], 0, 0, 0);
  }

  const int er = (lane >> 4) * 4;
  #pragma unroll
  for (int mi = 0; mi < 4; ++mi) {
    #pragma unroll
    for (int ni = 0; ni < 4; ++ni) {
      #pragma unroll
      for (int j = 0; j < 4; ++j) {
        const int r = brow + wr + mi * 16 + er + j;
        const int c = bcol + wc + ni * 16 + fr;
        float v = acc[mi][ni][j];
        if (MODE == 0) {
          v = (v + bias[c]) * scale;
          ((unsigned short*)Cout)[(size_t)r * DIM_ + c] = f2bf(v);
        } else if (MODE == 1) {
          v += frac[r] * bias[c];
          ((unsigned short*)Cout)[(size_t)r * DIM_ + c] = f2bf(v);
        } else {
          ((float*)Cout)[(size_t)r * DIM_ + c] = v + bias[c];
        }
      }
    }
  }
}

// ---------------------------------------------------------------------------
// Fused low-rank attention. Block = one (b,h), 64 Q-rows, 4 waves x 16 rows.
// Scores (16x256 per wave) held in registers; softmax via 16-lane shfl_xor
// groups; P through LDS as the MFMA-A layout adapter; V transposed in LDS.
// ---------------------------------------------------------------------------
__global__ __launch_bounds__(256) void attn_fused(
    const unsigned short* __restrict__ Qh,   // [4,4096,768] bf16 (pre-scaled by 1/8)
    const unsigned short* __restrict__ Kc,   // [4,256,768] bf16
    const unsigned short* __restrict__ Vc,   // [4,256,768] bf16
    unsigned short* __restrict__ ctx)        // [4,4096,768] bf16
{
  __shared__ unsigned short Vt[HD_][LK_];      // 32 KB: Vt[d][k] = V[k][d]
  __shared__ unsigned short Plds[4][16][LK_];  // 32 KB: per-wave P tiles
  const int tid  = threadIdx.x;
  const int lane = tid & 63;
  const int wave = tid >> 6;
  const int bh = blockIdx.y;
  const int b = bh / NH_, h = bh % NH_;
  const int qbase = blockIdx.x * 64;
  const int fr = lane & 15;
  const int fk = (lane >> 4) * 8;

  // stage V^T for this (b,h): V rows 256 x 64
  #pragma unroll
  for (int i = 0; i < 8; ++i) {
    const int row = i * 32 + (tid >> 3);
    const int c8  = (tid & 7) * 8;
    const unsigned short* src = Vc + (size_t)(b * LK_ + row) * DIM_ + h * HD_ + c8;
    us8 v = *(const us8*)src;
    #pragma unroll
    for (int j = 0; j < 8; ++j) Vt[c8 + j][row] = v[j];
  }

  // Q fragments (2 k-halves) straight from global
  const int qrow = qbase + wave * 16;
  const unsigned short* qp =
      Qh + (size_t)(b * SEQ_ + qrow + fr) * DIM_ + h * HD_ + fk;
  const bf8 aq0 = *(const bf8*)qp;
  const bf8 aq1 = *(const bf8*)(qp + 32);

  // scores: 16 tiles of 16x16 covering 256 keys
  f32x4 sc[16];
  const unsigned short* kb = Kc + (size_t)b * LK_ * DIM_ + h * HD_ + fk;
  #pragma unroll
  for (int t = 0; t < 16; ++t) {
    const unsigned short* kp = kb + (size_t)(t * 16 + fr) * DIM_;
    const bf8 b0 = *(const bf8*)kp;
    const bf8 b1 = *(const bf8*)(kp + 32);
    f32x4 a = (f32x4){0.f, 0.f, 0.f, 0.f};
    a = __builtin_amdgcn_mfma_f32_16x16x32_bf16(aq0, b0, a, 0, 0, 0);
    a = __builtin_amdgcn_mfma_f32_16x16x32_bf16(aq1, b1, a, 0, 0, 0);
    sc[t] = a;
  }

  // softmax over 256 cols per q-row; lane owns rows (lane>>4)*4+j, col fr+16t
  #pragma unroll
  for (int j = 0; j < 4; ++j) {
    float m = sc[0][j];
    #pragma unroll
    for (int t = 1; t < 16; ++t) m = fmaxf(m, sc[t][j]);
    m = fmaxf(m, __shfl_xor(m, 1));
    m = fmaxf(m, __shfl_xor(m, 2));
    m = fmaxf(m, __shfl_xor(m, 4));
    m = fmaxf(m, __shfl_xor(m, 8));
    float s = 0.f;
    #pragma unroll
    for (int t = 0; t < 16; ++t) { float p = __expf(sc[t][j] - m); sc[t][j] = p; s += p; }
    s += __shfl_xor(s, 1);
    s += __shfl_xor(s, 2);
    s += __shfl_xor(s, 4);
    s += __shfl_xor(s, 8);
    const float inv = 1.f / s;
    #pragma unroll
    for (int t = 0; t < 16; ++t) sc[t][j] *= inv;
  }

  // P -> LDS (layout adapter into MFMA A-fragment order)
  const int er = (lane >> 4) * 4;
  #pragma unroll
  for (int t = 0; t < 16; ++t)
    #pragma unroll
    for (int j = 0; j < 4; ++j)
      Plds[wave][er + j][t * 16 + fr] = f2bf(sc[t][j]);

  __syncthreads();   // covers Vt (cross-wave) and Plds (intra-wave) readiness

  // PV: context tile 16 x 64 per wave, K=256 in 8 steps of 32
  f32x4 acc[4];
  #pragma unroll
  for (int ct = 0; ct < 4; ++ct) acc[ct] = (f32x4){0.f, 0.f, 0.f, 0.f};
  #pragma unroll
  for (int ks = 0; ks < 8; ++ks) {
    const bf8 ap = *(const bf8*)&Plds[wave][fr][ks * 32 + fk];
    #pragma unroll
    for (int ct = 0; ct < 4; ++ct) {
      const bf8 bv = *(const bf8*)&Vt[ct * 16 + fr][ks * 32 + fk];
      acc[ct] = __builtin_amdgcn_mfma_f32_16x16x32_bf16(ap, bv, acc[ct], 0, 0, 0);
    }
  }

  #pragma unroll
  for (int ct = 0; ct < 4; ++ct)
    #pragma unroll
    for (int j = 0; j < 4; ++j) {
      const int r = qrow + er + j;
      const int c = h * HD_ + ct * 16 + fr;
      ctx[(size_t)(b * SEQ_ + r) * DIM_ + c] = f2bf(acc[ct][j]);
    }
}

// ---------------------------------------------------------------------------
extern "C" void kernel_launch(void* const* d_in, const int* in_sizes, int n_in,
                              void* d_out, int out_size, void* d_ws, size_t ws_size,
                              hipStream_t stream) {
  const float* query = (const float*)d_in[0];
  const float* key   = (const float*)d_in[1];
  const float* value = (const float*)d_in[2];
  const float* mask  = (const float*)d_in[3];
  const float* Wq    = (const float*)d_in[4];
  const float* bq    = (const float*)d_in[5];
  const float* Wk    = (const float*)d_in[6];
  const float* bk    = (const float*)d_in[7];
  const float* Wv    = (const float*)d_in[8];
  const float* bv    = (const float*)d_in[9];
  const float* Wo    = (const float*)d_in[10];
  const float* bo    = (const float*)d_in[11];
  float* out = (float*)d_out;

  char* ws = (char*)d_ws;
  unsigned short* Qh  = (unsigned short*)ws;                  // 25,165,824 B
  unsigned short* ctx = (unsigned short*)(ws + 25165824);     // 25,165,824 B
  unsigned short* pK  = (unsigned short*)(ws + 50331648);     //  1,572,864 B
  unsigned short* pV  = (unsigned short*)(ws + 51904512);     //  1,572,864 B
  unsigned short* Kc  = (unsigned short*)(ws + 53477376);     //  1,572,864 B
  unsigned short* Vc  = (unsigned short*)(ws + 55050240);     //  1,572,864 B
  float*          frac = (float*)(ws + 56623104);             //      4,096 B

  pool_kernel<<<dim3(1024), dim3(256), 0, stream>>>(key, value, mask, pK, pV, frac);
  gemm_bt<1, 0><<<dim3(128, 6), dim3(256), 0, stream>>>(query, Wq, bq, nullptr, Qh, 16384, 0.125f);
  gemm_bt<0, 1><<<dim3(8, 6), dim3(256), 0, stream>>>(pK, Wk, bk, frac, Kc, 1024, 1.f);
  gemm_bt<0, 1><<<dim3(8, 6), dim3(256), 0, stream>>>(pV, Wv, bv, frac, Vc, 1024, 1.f);
  attn_fused<<<dim3(64, 48), dim3(256), 0, stream>>>(Qh, Kc, Vc, ctx);
  gemm_bt<0, 2><<<dim3(128, 6), dim3(256), 0, stream>>>(ctx, Wo, bo, nullptr, out, 16384, 1.f);
}